// Round 1
// baseline (134.448 us; speedup 1.0000x reference)
//
#include <hip/hip_runtime.h>

#define FEAT 1024
#define TREE_DEPTH 10

// One wave (64 lanes) per sample; 4 waves per 256-thread block.
// Each lane owns 16 floats of x (4x float4, chunk index lane + 64*k) and the
// matching 16 floats of the y accumulator. Dot accumulates in double so the
// data-dependent sign decision matches the numpy reference to ~1e-7.
__global__ __launch_bounds__(256) void fff_kernel(
    const float* __restrict__ x,
    const float* __restrict__ Xw,
    const float* __restrict__ Yw,
    float* __restrict__ out,
    int nsamples)
{
    const int wave = threadIdx.x >> 6;
    const int lane = threadIdx.x & 63;
    const int s = blockIdx.x * 4 + wave;
    if (s >= nsamples) return;

    const float* xp = x + (size_t)s * FEAT;

    float4 xv[4];
#pragma unroll
    for (int k = 0; k < 4; ++k)
        xv[k] = *reinterpret_cast<const float4*>(xp + (size_t)(lane + 64 * k) * 4);

    float4 acc[4];
#pragma unroll
    for (int k = 0; k < 4; ++k)
        acc[k] = make_float4(0.f, 0.f, 0.f, 0.f);

    int cur = 0;
#pragma unroll
    for (int d = 0; d < TREE_DEPTH; ++d) {
        const float* Xr = Xw + (size_t)cur * FEAT;

        double p = 0.0;
#pragma unroll
        for (int k = 0; k < 4; ++k) {
            float4 xc = *reinterpret_cast<const float4*>(Xr + (size_t)(lane + 64 * k) * 4);
            p += (double)xv[k].x * (double)xc.x;
            p += (double)xv[k].y * (double)xc.y;
            p += (double)xv[k].z * (double)xc.z;
            p += (double)xv[k].w * (double)xc.w;
        }

        // 64-lane butterfly reduce (wave = 64 on CDNA).
#pragma unroll
        for (int off = 32; off >= 1; off >>= 1)
            p += __shfl_xor(p, off, 64);

        const float lam = (float)p;
        const float* Yr = Yw + (size_t)cur * FEAT;
#pragma unroll
        for (int k = 0; k < 4; ++k) {
            float4 yc = *reinterpret_cast<const float4*>(Yr + (size_t)(lane + 64 * k) * 4);
            acc[k].x += lam * yc.x;
            acc[k].y += lam * yc.y;
            acc[k].z += lam * yc.z;
            acc[k].w += lam * yc.w;
        }

        cur = cur * 2 + 1 + (p > 0.0 ? 1 : 0);
    }

    float* op = out + (size_t)s * FEAT;
#pragma unroll
    for (int k = 0; k < 4; ++k)
        *reinterpret_cast<float4*>(op + (size_t)(lane + 64 * k) * 4) = acc[k];
}

extern "C" void kernel_launch(void* const* d_in, const int* in_sizes, int n_in,
                              void* d_out, int out_size, void* d_ws, size_t ws_size,
                              hipStream_t stream) {
    const float* oldx = (const float*)d_in[0];
    const float* Xw   = (const float*)d_in[1];
    const float* Yw   = (const float*)d_in[2];
    float* out = (float*)d_out;

    const int nsamples = in_sizes[0] / FEAT;          // 32768
    const int blocks = (nsamples + 3) / 4;            // 4 samples per block

    fff_kernel<<<blocks, 256, 0, stream>>>(oldx, Xw, Yw, out, nsamples);
}